// Round 8
// baseline (97.897 us; speedup 1.0000x reference)
//
#include <hip/hip_runtime.h>
#include <hip/hip_bf16.h>

// EmbeddingLoss: loss = sum_{i<j} [ same ? mse : max(0,1-mse) ] / (B*(B-1))
// mse_ij = (sq_i + sq_j - 2*gram_ij)/D, gram = E E^T.
// Round 8: fp8 e4m3 gram (halves staged bytes; fp8 MFMA = bf16 rate) +
// 4 blocks/CU (32KB LDS, ~120 VGPR) for load-issue concurrency. R4's
// counted-vmcnt dbuf skeleton retained. sq stays fp32 (exact).

#define BN 8192
#define DK 256
#define NT 64                      // BN/128 tiles per dim
#define NBLK (NT * (NT + 1) / 2)   // 2080 upper-tri tiles = 8*260

typedef float f32x4 __attribute__((ext_vector_type(4)));

typedef const __attribute__((address_space(1))) void* gas_vp;
typedef __attribute__((address_space(3))) void* las_vp;

// float -> OCP e4m3fn, RTN-even (software; inputs |x| << 448, no NaN/Inf)
static __device__ __forceinline__ unsigned char f2e4m3(float f) {
    unsigned u = __builtin_bit_cast(unsigned, f);
    unsigned s = (u >> 24) & 0x80;
    int e = (int)((u >> 23) & 0xff) - 127;
    unsigned m = u & 0x7fffff;
    if (e < -9) return (unsigned char)s;          // underflow -> +-0
    if (e >= -6) {                                // normal e4m3
        unsigned mant = m >> 20;
        unsigned rest = m & 0xfffff;
        unsigned round = (rest > 0x80000u) || (rest == 0x80000u && (mant & 1));
        unsigned val = ((unsigned)(e + 7) << 3) | mant;
        val += round;                             // carry into exp is correct
        return (unsigned char)(s | val);
    }
    // subnormal e4m3: value = mant * 2^-9, e in [-9,-7]
    int shift = -6 - e;                           // 1..3
    unsigned full = 0x800000u | m;
    unsigned rb = 20 + shift;
    unsigned mant = full >> rb;
    unsigned rest = full & ((1u << rb) - 1);
    unsigned half = 1u << (rb - 1);
    unsigned round = (rest > half) || (rest == half && (mant & 1));
    mant += round;
    return (unsigned char)(s | mant);
}

// ---------------- prep: fp32->fp8 (ws) + fp32 row norms (ws), zero out -----
__global__ __launch_bounds__(256) void embl_prep(
    const float* __restrict__ E, unsigned char* __restrict__ E8,
    float* __restrict__ sq, float* __restrict__ out)
{
    const int lane = threadIdx.x & 63;
    const int wid  = threadIdx.x >> 6;
    const int row  = blockIdx.x * 4 + wid;    // one row per wave
    if (blockIdx.x == 0 && threadIdx.x == 0) *out = 0.0f;
    const float4 v = *(const float4*)(E + row * DK + lane * 4);
    float s = v.x*v.x + v.y*v.y + v.z*v.z + v.w*v.w;
    uchar4 o;
    o.x = f2e4m3(v.x); o.y = f2e4m3(v.y); o.z = f2e4m3(v.z); o.w = f2e4m3(v.w);
    *(uchar4*)(E8 + row * DK + lane * 4) = o;
    #pragma unroll
    for (int off = 32; off > 0; off >>= 1) s += __shfl_xor(s, off, 64);
    if (lane == 0) sq[row] = s;
}

// ---------------- main: 128x128 fp8 gram tile, 4 waves, dbuf pipeline ------
__global__ __launch_bounds__(256, 4) void embl_gram(
    const unsigned char* __restrict__ E8, const float* __restrict__ sq,
    const int* __restrict__ lab, float* __restrict__ out)
{
    __shared__ alignas(16) unsigned char As[2][128 * 64];   // 8KB per buf
    __shared__ alignas(16) unsigned char Bs[2][128 * 64];
    __shared__ float wpart[4];

    // XCD-aware chunked swizzle, bijective: 2080 = 8 * 260
    const int bid = (blockIdx.x & 7) * 260 + (blockIdx.x >> 3);
    // upper-tri decode: bid -> (ti, tj), ti <= tj
    int t = bid, ti = 0, rl = NT;
    while (t >= rl) { t -= rl; --rl; ++ti; }
    const int tj = ti + t;

    const int tid  = threadIdx.x;
    const int lane = tid & 63;
    const int wid  = tid >> 6;
    const int wr   = wid >> 1;          // 0..1 -> 64-row half
    const int wc   = wid & 1;           // 0..1 -> 64-col half

    const int lcol = lane & 15;         // MFMA frag row/col index
    const int kg   = lane >> 4;         // 0..3 k-group (8B each)
    const int lsw  = lcol & 3;          // read-side XOR key (== row & 3)

    const char* E8c = (const char*)E8;
    const int arow = ti * 128;
    const int brow = tj * 128;

    // stage one op K-tile (128 rows x 64 fp8 = 8KB = 512x16B): 2 loads/thr.
    // Linear LDS dest chunk c; source chunk XOR-swizzled (involution, 2 bits).
#define STAGE(dst, grow, kt)                                                   \
    {                                                                          \
        _Pragma("unroll")                                                      \
        for (int it_ = 0; it_ < 2; ++it_) {                                    \
            const int c_   = it_ * 256 + tid;   /* 0..511 */                   \
            const int row_ = c_ >> 2;           /* 0..127 */                   \
            const int sch_ = (c_ & 3) ^ (row_ & 3);                            \
            __builtin_amdgcn_global_load_lds(                                  \
                (gas_vp)(E8c + (long)((grow) + row_) * 256 + (kt) * 64 + sch_ * 16), \
                (las_vp)((char*)(dst) + c_ * 16), 16, 0, 0);                   \
        }                                                                      \
    }

#define WAITVM(N)                                                              \
    {                                                                          \
        asm volatile("s_waitcnt vmcnt(" #N ")" ::: "memory");                  \
        __builtin_amdgcn_sched_barrier(0);                                     \
        __builtin_amdgcn_s_barrier();                                          \
        __builtin_amdgcn_sched_barrier(0);                                     \
    }

    // swizzled 8B fragment read: row stride 64B (4x16B chunks), chunk ^= row&3
#define LD8(base, row, ks)                                                     \
    (*(const long*)((const char*)(base) + (long)(row) * 64 +                   \
        ((((ks) * 2 + (kg >> 1)) ^ lsw) * 16) + (kg & 1) * 8))

#define TILE(buf)                                                              \
    {                                                                          \
        long a_[4][2], b_[4][2];                                               \
        _Pragma("unroll")                                                      \
        for (int ks = 0; ks < 2; ++ks) {                                       \
            _Pragma("unroll")                                                  \
            for (int m_ = 0; m_ < 4; ++m_) {                                   \
                a_[m_][ks] = LD8(&As[buf][0], wr * 64 + m_ * 16 + lcol, ks);   \
                b_[m_][ks] = LD8(&Bs[buf][0], wc * 64 + m_ * 16 + lcol, ks);   \
            }                                                                  \
        }                                                                      \
        __builtin_amdgcn_s_setprio(1);                                         \
        _Pragma("unroll")                                                      \
        for (int ks = 0; ks < 2; ++ks)                                         \
        _Pragma("unroll")                                                      \
        for (int m_ = 0; m_ < 4; ++m_)                                         \
        _Pragma("unroll")                                                      \
        for (int n_ = 0; n_ < 4; ++n_)                                         \
            acc[m_][n_] = __builtin_amdgcn_mfma_f32_16x16x32_fp8_fp8(          \
                a_[m_][ks], b_[n_][ks], acc[m_][n_], 0, 0, 0);                 \
        __builtin_amdgcn_s_setprio(0);                                         \
        __builtin_amdgcn_sched_barrier(0);                                     \
        __builtin_amdgcn_s_barrier();   /* all waves done reading buf */       \
        __builtin_amdgcn_sched_barrier(0);                                     \
    }

    f32x4 acc[4][4] = {};

    // prologue: stage K-tiles 0,1 (8 loads/thread outstanding)
    STAGE(As[0], arow, 0); STAGE(Bs[0], brow, 0);
    STAGE(As[1], arow, 1); STAGE(Bs[1], brow, 1);
    WAITVM(4);                          // t0 landed (t1 in flight)
    TILE(0);
    STAGE(As[0], arow, 2); STAGE(Bs[0], brow, 2);
    WAITVM(4);                          // t1 landed (t2 in flight)
    TILE(1);
    STAGE(As[1], arow, 3); STAGE(Bs[1], brow, 3);
    WAITVM(4);                          // t2 landed (t3 in flight)
    TILE(0);
    WAITVM(0);                          // t3 landed
    TILE(1);

    // ---- epilogue: C/D layout col=lane&15, row=(lane>>4)*4+reg ------------
    const int gi0 = arow + wr * 64;
    const int gj0 = brow + wc * 64;
    float lsum = 0.0f;

#define EPI(MASKED)                                                            \
    {                                                                          \
        float sqj_[4]; int lj_[4], jj_[4];                                     \
        _Pragma("unroll")                                                      \
        for (int n_ = 0; n_ < 4; ++n_) {                                       \
            jj_[n_] = gj0 + n_ * 16 + lcol;                                    \
            sqj_[n_] = sq[jj_[n_]]; lj_[n_] = lab[jj_[n_]];                    \
        }                                                                      \
        _Pragma("unroll")                                                      \
        for (int m_ = 0; m_ < 4; ++m_) {                                       \
            const int ibase = gi0 + m_ * 16 + kg * 4;                          \
            _Pragma("unroll")                                                  \
            for (int r_ = 0; r_ < 4; ++r_) {                                   \
                const int i_ = ibase + r_;                                     \
                const float sqi_ = sq[i_]; const int li_ = lab[i_];            \
                _Pragma("unroll")                                              \
                for (int n_ = 0; n_ < 4; ++n_) {                               \
                    const float mse_ =                                         \
                        (sqi_ + sqj_[n_] - 2.0f * acc[m_][n_][r_]) *           \
                        (1.0f / 256.0f);                                       \
                    float v_ = (li_ == lj_[n_]) ? mse_                         \
                                                : fmaxf(0.0f, 1.0f - mse_);    \
                    if (MASKED && i_ >= jj_[n_]) v_ = 0.0f;                    \
                    lsum += v_;                                                \
                }                                                              \
            }                                                                  \
        }                                                                      \
    }

    if (ti == tj) { EPI(1) } else { EPI(0) }

    #pragma unroll
    for (int off = 32; off > 0; off >>= 1) lsum += __shfl_xor(lsum, off, 64);
    if (lane == 0) wpart[wid] = lsum;
    __syncthreads();
    if (tid == 0) {
        const float scale = 1.0f / ((float)BN * (float)(BN - 1));
        atomicAdd(out, (wpart[0] + wpart[1] + wpart[2] + wpart[3]) * scale);
    }
}

extern "C" void kernel_launch(void* const* d_in, const int* in_sizes, int n_in,
                              void* d_out, int out_size, void* d_ws, size_t ws_size,
                              hipStream_t stream) {
    const float* E   = (const float*)d_in[0];
    const int*   lab = (const int*)d_in[1];
    float*       out = (float*)d_out;

    unsigned char* E8 = (unsigned char*)d_ws;                       // 2 MiB
    float*         sq = (float*)((char*)d_ws + (size_t)BN * DK);    // 32 KiB

    embl_prep<<<BN / 4, 256, 0, stream>>>(E, E8, sq, out);
    embl_gram<<<NBLK, 256, 0, stream>>>(E8, sq, lab, out);
}